// Round 7
// baseline (2226.707 us; speedup 1.0000x reference)
//
#include <hip/hip_runtime.h>
#include <hip/hip_bf16.h>

#define BB   256   // batch
#define TT   512   // time steps
#define XSZ  256   // input size
#define HSZ  256   // hidden size

typedef __bf16 bf16_t;
typedef __attribute__((ext_vector_type(8))) __bf16 bf16x8;
typedef __attribute__((ext_vector_type(4))) float  f32x4;
typedef __attribute__((ext_vector_type(4))) unsigned uint4v;

__device__ __forceinline__ f32x4 splat4(float v) { f32x4 r = {v, v, v, v}; return r; }

// ---------------- prep: bias[g*256+c] = bx_g[c] + bh_g[c] ----------------
__global__ void prep_bias(const float* bx0, const float* bh0, const float* bx1, const float* bh1,
                          const float* bx2, const float* bh2, const float* bx3, const float* bh3,
                          float* bias) {
  const float* bxs[4] = {bx0, bx1, bx2, bx3};
  const float* bhs[4] = {bh0, bh1, bh2, bh3};
  int g = blockIdx.x, c = threadIdx.x;
  bias[g * 256 + c] = bxs[g][c] + bhs[g][c];
}

// ---------------- prep: fragment-linear, GATE-INTERLEAVED weight pack ----------------
// Chunk cid = j*256 + w*32 + nt*16 + kt (j=col-block 0..3, w=wave 0..7, nt 0..1, kt 0..15).
// Lane L holds 16 B: tile col tc = L&15 -> gate = tc&3, hidden col
// hc = j*64 + w*8 + nt*4 + (tc>>2); k = kt*32 + (L>>4)*8 .. +7. k<256 -> Wh[gate], else Wx[gate].
__global__ void prep_wtf(const float* wx0, const float* wh0, const float* wx1, const float* wh1,
                         const float* wx2, const float* wh2, const float* wx3, const float* wh3,
                         bf16_t* Wtf) {
  const float* whs[4] = {wh0, wh1, wh2, wh3};
  const float* wxs[4] = {wx0, wx1, wx2, wx3};
  int id = blockIdx.x * 256 + threadIdx.x;    // 65536 = 1024 chunks x 64 lanes
  int L  = id & 63;
  int kt = (id >> 6) & 15;
  int nt = (id >> 10) & 1;
  int w  = (id >> 11) & 7;
  int j  = (id >> 14) & 3;
  int tc   = L & 15;
  int gate = tc & 3;
  int hc   = j * 64 + w * 8 + nt * 4 + (tc >> 2);
  int k0   = kt * 32 + (L >> 4) * 8;
  const float* src = (k0 < 256) ? (whs[gate] + (size_t)k0 * 256 + hc)
                                : (wxs[gate] + (size_t)(k0 - 256) * 256 + hc);
  bf16x8 v;
#pragma unroll
  for (int i = 0; i < 8; ++i) v[i] = (__bf16)src[(size_t)i * 256];
  reinterpret_cast<bf16x8*>(Wtf)[id] = v;
}

// ---------------- prep: x f32 -> bf16 ----------------
__global__ void prep_xbf(const float* __restrict__ x, bf16_t* __restrict__ xb) {
  size_t id = (size_t)blockIdx.x * 256 + threadIdx.x;   // x8 elements
  const float* p = x + id * 8;
  f32x4 lo = *reinterpret_cast<const f32x4*>(p);
  f32x4 hi = *reinterpret_cast<const f32x4*>(p + 4);
  bf16x8 v;
#pragma unroll
  for (int i = 0; i < 4; ++i) { v[i] = (__bf16)lo[i]; v[i + 4] = (__bf16)hi[i]; }
  reinterpret_cast<bf16x8*>(xb)[id] = v;
}

// ---------------- main sequential LSTM ----------------
// 64 blocks = 16 groups (16 batch rows) x 4 column-blocks (64 hidden cols).
// All weights in VGPRs (Bh[2][8] + Bx[2][8]). Gate-interleaved n-tiles ->
// in-wave 4-lane butterfly combine, publish immediately after MFMA+combine.
// One barrier/step (hxl dedupe). Self-validating {seq16,h} exchange via MALL.
template <bool XBF>
__global__ __launch_bounds__(512, 2)
void lstm_seq(const void* __restrict__ xsrc, const bf16_t* __restrict__ Wtf,
              const float* __restrict__ bias, unsigned* __restrict__ hseq,
              float* __restrict__ out)
{
  __shared__ __align__(16) char hxl[2][8192];   // h A-frags, 8 kt x 1 KB, dbuf

  const int tid  = threadIdx.x;
  const int w    = tid >> 6;
  const int lane = tid & 63;
  const int l15  = lane & 15, l4 = lane >> 4;
  const int bid  = blockIdx.x;
  const int g    = bid >> 2, j = bid & 3;
  const int b0   = g * 16;
  const int gate = l15 & 3;          // this lane's gate within the 4-lane group
  const int hcg  = l15 >> 2;         // hidden-col sub-index 0..3
  const bool isg = (gate == 2);

  const float*  xf32 = (const float*)xsrc;
  const bf16_t* xbf  = (const bf16_t*)xsrc;

  // ---- all weights -> VGPRs
  const char* wbase = (const char*)Wtf + (size_t)(j * 256 + w * 32) * 1024 + lane * 16;
  bf16x8 Bh[2][8], Bx[2][8];
#pragma unroll
  for (int nt = 0; nt < 2; ++nt)
#pragma unroll
    for (int kt = 0; kt < 8; ++kt) {
      Bh[nt][kt] = *reinterpret_cast<const bf16x8*>(wbase + (nt * 16 + kt) * 1024);
      Bx[nt][kt] = *reinterpret_cast<const bf16x8*>(wbase + (nt * 16 + 8 + kt) * 1024);
    }

  float bias_v[2];
#pragma unroll
  for (int nt = 0; nt < 2; ++nt)
    bias_v[nt] = bias[gate * 256 + j * 64 + w * 8 + nt * 4 + hcg];

  f32x4 cst0 = {0.f, 0.f, 0.f, 0.f};
  f32x4 cst1 = {0.f, 0.f, 0.f, 0.f};

  // ---- prologue: acc_x = bias + x_0 @ Wx
  f32x4 acc_x0 = splat4(bias_v[0]);
  f32x4 acc_x1 = splat4(bias_v[1]);
#pragma unroll
  for (int k8 = 0; k8 < 8; ++k8) {
    bf16x8 a;
    if constexpr (XBF) {
      a = *reinterpret_cast<const bf16x8*>(
          xbf + (size_t)(b0 + l15) * (TT * XSZ) + k8 * 32 + l4 * 8);
    } else {
      const float* xp = xf32 + (size_t)(b0 + l15) * (TT * XSZ) + k8 * 32 + l4 * 8;
      f32x4 lo = *reinterpret_cast<const f32x4*>(xp);
      f32x4 hi = *reinterpret_cast<const f32x4*>(xp + 4);
#pragma unroll
      for (int i = 0; i < 4; ++i) { a[i] = (__bf16)lo[i]; a[i + 4] = (__bf16)hi[i]; }
    }
    acc_x0 = __builtin_amdgcn_mfma_f32_16x16x32_bf16(a, Bx[0][k8], acc_x0, 0, 0, 0);
    acc_x1 = __builtin_amdgcn_mfma_f32_16x16x32_bf16(a, Bx[1][k8], acc_x1, 0, 0, 0);
  }

#pragma unroll 1
  for (int t = 0; t < TT; ++t) {
    f32x4 acc0 = acc_x0;
    f32x4 acc1 = acc_x1;

    if (t > 0) {
      // ---- one-round-trip exchange: 8 self-validating h dwords per lane
      const unsigned* hp = hseq + (size_t)(t & 1) * 65536
                         + (size_t)(b0 + l15) * HSZ + w * 32 + l4 * 8;
      const unsigned tg = (unsigned)t;
      uint4v A, B;
      for (;;) {
        asm volatile("global_load_dwordx4 %0, %2, off sc0 sc1\n\t"
                     "global_load_dwordx4 %1, %2, off offset:16 sc0 sc1\n\t"
                     "s_waitcnt vmcnt(0)"
                     : "=&v"(A), "=&v"(B) : "v"(hp) : "memory");
        bool ok = ((A[0] >> 16) == tg) & ((A[1] >> 16) == tg) &
                  ((A[2] >> 16) == tg) & ((A[3] >> 16) == tg) &
                  ((B[0] >> 16) == tg) & ((B[1] >> 16) == tg) &
                  ((B[2] >> 16) == tg) & ((B[3] >> 16) == tg);
        if (__all((int)ok)) break;
        __builtin_amdgcn_s_sleep(1);
      }
      __builtin_amdgcn_sched_barrier(0);
      // pack 8 lo16 -> bf16x8 A-frag; wave w supplies kt=w chunk
      unsigned p0 = (A[0] & 0xFFFFu) | (A[1] << 16);
      unsigned p1 = (A[2] & 0xFFFFu) | (A[3] << 16);
      unsigned p2 = (B[0] & 0xFFFFu) | (B[1] << 16);
      unsigned p3 = (B[2] & 0xFFFFu) | (B[3] << 16);
      uint4v pk = {p0, p1, p2, p3};
      *reinterpret_cast<uint4v*>(hxl[t & 1] + w * 1024 + lane * 16) = pk;
    }
    __syncthreads();   // hxl[t&1] complete (t=0: plain sync)

    if (t > 0) {
      // ---- critical MFMAs: acc += h(t) @ Wh (A from LDS, B from VGPRs)
#pragma unroll
      for (int kt = 0; kt < 8; ++kt) {
        bf16x8 a = *reinterpret_cast<const bf16x8*>(hxl[t & 1] + kt * 1024 + lane * 16);
        acc0 = __builtin_amdgcn_mfma_f32_16x16x32_bf16(a, Bh[0][kt], acc0, 0, 0, 0);
        acc1 = __builtin_amdgcn_mfma_f32_16x16x32_bf16(a, Bh[1][kt], acc1, 0, 0, 0);
      }
    }

    // ---- in-wave butterfly combine (4-lane gate groups), per n-tile
    float hsel[2], csel[2];
#pragma unroll
    for (int nt = 0; nt < 2; ++nt) {
      f32x4 acc = nt ? acc1 : acc0;
      // branchless activation: tanh(v) = 2*sigmoid(2v)-1
      f32x4 av;
#pragma unroll
      for (int r = 0; r < 4; ++r) {
        float p = isg ? 2.f * acc[r] : acc[r];
        float s = 1.f / (1.f + __expf(-p));
        av[r] = isg ? (2.f * s - 1.f) : s;
      }
      f32x4 bv, v0, v1, c0, c1;
#pragma unroll
      for (int r = 0; r < 4; ++r) bv[r] = __shfl_xor(av[r], 1);
#pragma unroll
      for (int r = 0; r < 4; ++r) {
        v0[r] = (gate & 1) ? bv[r] : av[r];   // even-gate value (i or g)
        v1[r] = (gate & 1) ? av[r] : bv[r];   // odd-gate value (f or o)
      }
#pragma unroll
      for (int r = 0; r < 4; ++r) { c0[r] = __shfl_xor(v0[r], 2); c1[r] = __shfl_xor(v1[r], 2); }
      f32x4 hv;
      f32x4 cs = nt ? cst1 : cst0;
#pragma unroll
      for (int r = 0; r < 4; ++r) {
        float iv = (gate & 2) ? c0[r] : v0[r];
        float fv = (gate & 2) ? c1[r] : v1[r];
        float gv = (gate & 2) ? v0[r] : c0[r];
        float ov = (gate & 2) ? v1[r] : c1[r];
        float cn = fv * cs[r] + iv * gv;
        cs[r] = cn;
        float s2 = 1.f / (1.f + __expf(-2.f * cn));
        hv[r] = ov * (2.f * s2 - 1.f);
      }
      if (nt) cst1 = cs; else cst0 = cs;
      // this lane publishes row r = gate (static selects, no dyn indexing)
      float hs = (gate == 0) ? hv[0] : (gate == 1) ? hv[1] : (gate == 2) ? hv[2] : hv[3];
      float cc = (gate == 0) ? cs[0] : (gate == 1) ? cs[1] : (gate == 2) ? cs[2] : cs[3];
      hsel[nt] = hs;
      csel[nt] = cc;
    }

    if (t + 1 < TT) {
      // ---- publish h(t+1): each lane stores its (row = l4*4+gate, 2 hcols)
#pragma unroll
      for (int nt = 0; nt < 2; ++nt) {
        __bf16 hb16 = (__bf16)hsel[nt];
        unsigned hv = ((unsigned)(t + 1) << 16)
                    | (unsigned)__builtin_bit_cast(unsigned short, hb16);
        unsigned* hp2 = hseq + (size_t)((t + 1) & 1) * 65536
                      + (size_t)(b0 + l4 * 4 + gate) * HSZ
                      + (j * 64 + w * 8 + nt * 4 + hcg);
        asm volatile("global_store_dword %0, %1, off sc0 sc1" :: "v"(hp2), "v"(hv) : "memory");
      }

      // ---- shadowed: acc_x = bias + x_{t+1} @ Wx (B in VGPRs)
      acc_x0 = splat4(bias_v[0]);
      acc_x1 = splat4(bias_v[1]);
#pragma unroll
      for (int k8 = 0; k8 < 8; ++k8) {
        bf16x8 a;
        if constexpr (XBF) {
          a = *reinterpret_cast<const bf16x8*>(
              xbf + (size_t)(b0 + l15) * (TT * XSZ) + (size_t)(t + 1) * XSZ + k8 * 32 + l4 * 8);
        } else {
          const float* xp = xf32 + (size_t)(b0 + l15) * (TT * XSZ)
                          + (size_t)(t + 1) * XSZ + k8 * 32 + l4 * 8;
          f32x4 lo = *reinterpret_cast<const f32x4*>(xp);
          f32x4 hi = *reinterpret_cast<const f32x4*>(xp + 4);
#pragma unroll
          for (int i = 0; i < 4; ++i) { a[i] = (__bf16)lo[i]; a[i + 4] = (__bf16)hi[i]; }
        }
        acc_x0 = __builtin_amdgcn_mfma_f32_16x16x32_bf16(a, Bx[0][k8], acc_x0, 0, 0, 0);
        acc_x1 = __builtin_amdgcn_mfma_f32_16x16x32_bf16(a, Bx[1][k8], acc_x1, 0, 0, 0);
      }
    } else {
      // ---- final step: emit (h_T, c_T) f32
#pragma unroll
      for (int nt = 0; nt < 2; ++nt) {
        float* op = out + (size_t)(b0 + l4 * 4 + gate) * HSZ
                  + (j * 64 + w * 8 + nt * 4 + hcg);
        op[0] = hsel[nt];
        op[(size_t)BB * HSZ] = csel[nt];
      }
    }
  }
}

extern "C" void kernel_launch(void* const* d_in, const int* in_sizes, int n_in,
                              void* d_out, int out_size, void* d_ws, size_t ws_size,
                              hipStream_t stream) {
  const float* x = (const float*)d_in[0];
  const float *wx[4], *wh[4], *bx[4], *bh[4];
  for (int g = 0; g < 4; ++g) {          // dict order: wx, wh, bx, bh per gate (i,f,g,o)
    wx[g] = (const float*)d_in[1 + 4 * g];
    wh[g] = (const float*)d_in[2 + 4 * g];
    bx[g] = (const float*)d_in[3 + 4 * g];
    bh[g] = (const float*)d_in[4 + 4 * g];
  }

  char* ws = (char*)d_ws;
  float*    bias = (float*)ws;                                   // 4 KB
  bf16_t*   Wtf  = (bf16_t*)(ws + 4096);                         // 1 MB
  unsigned* hseq = (unsigned*)(ws + 4096 + 1048576);             // 512 KB (2 x 64K dwords)
  bf16_t*   xbf  = (bf16_t*)(ws + 4096 + 1048576 + 524288);      // 64 MB (optional)
  const size_t need_xbf = 4096 + 1048576 + 524288 + (size_t)BB * TT * XSZ * 2;

  prep_bias<<<dim3(4), dim3(256), 0, stream>>>(bx[0], bh[0], bx[1], bh[1],
                                               bx[2], bh[2], bx[3], bh[3], bias);
  prep_wtf<<<dim3(256), dim3(256), 0, stream>>>(wx[0], wh[0], wx[1], wh[1],
                                                wx[2], wh[2], wx[3], wh[3], Wtf);
  if (ws_size >= need_xbf) {
    prep_xbf<<<dim3((BB * TT * XSZ / 8) / 256), dim3(256), 0, stream>>>(x, xbf);
    lstm_seq<true><<<dim3(64), dim3(512), 0, stream>>>(xbf, Wtf, bias, hseq,
                                                       (float*)d_out);
  } else {
    lstm_seq<false><<<dim3(64), dim3(512), 0, stream>>>(x, Wtf, bias, hseq,
                                                        (float*)d_out);
  }
}

// Round 8
// 1876.996 us; speedup vs baseline: 1.1863x; 1.1863x over previous
//
#include <hip/hip_runtime.h>
#include <hip/hip_bf16.h>

#define BB   256   // batch
#define TT   512   // time steps
#define XSZ  256   // input size
#define HSZ  256   // hidden size

typedef __bf16 bf16_t;
typedef __attribute__((ext_vector_type(8))) __bf16 bf16x8;
typedef __attribute__((ext_vector_type(4))) float  f32x4;
typedef __attribute__((ext_vector_type(4))) unsigned uint4v;

__device__ __forceinline__ f32x4 splat4(float v) { f32x4 r = {v, v, v, v}; return r; }

// ---------------- prep: bias[g*256+c] = bx_g[c] + bh_g[c] ----------------
__global__ void prep_bias(const float* bx0, const float* bh0, const float* bx1, const float* bh1,
                          const float* bx2, const float* bh2, const float* bx3, const float* bh3,
                          float* bias) {
  const float* bxs[4] = {bx0, bx1, bx2, bx3};
  const float* bhs[4] = {bh0, bh1, bh2, bh3};
  int g = blockIdx.x, c = threadIdx.x;
  bias[g * 256 + c] = bxs[g][c] + bhs[g][c];
}

// ---------------- prep: fragment-linear, GATE-INTERLEAVED weight pack ----------------
// Chunk cid = (j*8 + w)*16 + kts (j=col-block 0..7, w=wave 0..7, kts 0..15).
// Lane L holds 16 B: tile col tc = L&15 -> gate = tc&3, hidden col
// hc = j*32 + w*4 + (tc>>2); k0 = kts*32 + (L>>4)*8. k0<256 -> Wh[gate], else Wx[gate].
__global__ void prep_wtf(const float* wx0, const float* wh0, const float* wx1, const float* wh1,
                         const float* wx2, const float* wh2, const float* wx3, const float* wh3,
                         bf16_t* Wtf) {
  const float* whs[4] = {wh0, wh1, wh2, wh3};
  const float* wxs[4] = {wx0, wx1, wx2, wx3};
  int id  = blockIdx.x * 256 + threadIdx.x;   // 65536 = 1024 chunks x 64 lanes
  int L   = id & 63;
  int kts = (id >> 6) & 15;
  int w   = (id >> 10) & 7;
  int j   = (id >> 13) & 7;
  int tc   = L & 15;
  int gate = tc & 3;
  int hc   = j * 32 + w * 4 + (tc >> 2);
  int k0   = kts * 32 + (L >> 4) * 8;
  const float* src = (k0 < 256) ? (whs[gate] + (size_t)k0 * 256 + hc)
                                : (wxs[gate] + (size_t)(k0 - 256) * 256 + hc);
  bf16x8 v;
#pragma unroll
  for (int i = 0; i < 8; ++i) v[i] = (__bf16)src[(size_t)i * 256];
  reinterpret_cast<bf16x8*>(Wtf)[id] = v;
}

// ---------------- prep: x f32 -> bf16 ----------------
__global__ void prep_xbf(const float* __restrict__ x, bf16_t* __restrict__ xb) {
  size_t id = (size_t)blockIdx.x * 256 + threadIdx.x;   // x8 elements
  const float* p = x + id * 8;
  f32x4 lo = *reinterpret_cast<const f32x4*>(p);
  f32x4 hi = *reinterpret_cast<const f32x4*>(p + 4);
  bf16x8 v;
#pragma unroll
  for (int i = 0; i < 4; ++i) { v[i] = (__bf16)lo[i]; v[i + 4] = (__bf16)hi[i]; }
  reinterpret_cast<bf16x8*>(xb)[id] = v;
}

// ---------------- main sequential LSTM ----------------
// 128 blocks = 16 groups (16 batch rows) x 8 column-blocks (32 hidden cols x
// 4 gates, gate-interleaved). 8 waves/block, ONE 16x16 n-tile per wave
// (4 hidden cols x 4 gates). Bh[8] in VGPRs (32 regs - stays resident),
// Bx in LDS. In-wave 4-lane butterfly gate combine -> publish right after
// MFMA. ONE barrier per step. Self-validating {seq16,h} MALL exchange.
template <bool XBF>
__global__ __launch_bounds__(512, 2)
void lstm_seq(const void* __restrict__ xsrc, const bf16_t* __restrict__ Wtf,
              const float* __restrict__ bias, unsigned* __restrict__ hseq,
              float* __restrict__ out)
{
  __shared__ __align__(16) char bxlds[65536];   // Wx slices, fragment-linear
  __shared__ __align__(16) char hxl[2][8192];   // h A-frags, 8 kt x 1 KB, dbuf

  const int tid  = threadIdx.x;
  const int w    = tid >> 6;
  const int lane = tid & 63;
  const int l15  = lane & 15, l4 = lane >> 4;
  const int bid  = blockIdx.x;
  const int g    = bid >> 3, j = bid & 7;
  const int b0   = g * 16;
  const int gate = l15 & 3;          // lane's gate within its 4-lane group
  const int hcg  = l15 >> 2;         // hidden-col sub-index 0..3
  const bool isg = (gate == 2);

  const float*  xf32 = (const float*)xsrc;
  const bf16_t* xbf  = (const bf16_t*)xsrc;

  // ---- setup: Bh (kts 0..7) -> VGPRs; Bx (kts 8..15) -> LDS (wave-private)
  const char* wbase = (const char*)Wtf + ((size_t)(j * 8 + w) * 16) * 1024 + lane * 16;
  bf16x8 Bh[8];
#pragma unroll
  for (int kt = 0; kt < 8; ++kt)
    Bh[kt] = *reinterpret_cast<const bf16x8*>(wbase + kt * 1024);
#pragma unroll
  for (int q = 0; q < 8; ++q) {
    bf16x8 v = *reinterpret_cast<const bf16x8*>(wbase + (8 + q) * 1024);
    *reinterpret_cast<bf16x8*>(bxlds + (w * 8 + q) * 1024 + lane * 16) = v;
  }

  const float bias_v = bias[gate * 256 + j * 32 + w * 4 + hcg];

  f32x4 cst = {0.f, 0.f, 0.f, 0.f};   // c for rows l4*4+0..3, col j*32+w*4+hcg

  __syncthreads();   // bxlds ready

  // ---- prologue: acc_x = bias + x_0 @ Wx (split accumulator chains)
  f32x4 axa = splat4(bias_v);
  f32x4 axb = {0.f, 0.f, 0.f, 0.f};
#pragma unroll
  for (int k8 = 0; k8 < 8; ++k8) {
    bf16x8 a;
    if constexpr (XBF) {
      a = *reinterpret_cast<const bf16x8*>(
          xbf + (size_t)(b0 + l15) * (TT * XSZ) + k8 * 32 + l4 * 8);
    } else {
      const float* xp = xf32 + (size_t)(b0 + l15) * (TT * XSZ) + k8 * 32 + l4 * 8;
      f32x4 lo = *reinterpret_cast<const f32x4*>(xp);
      f32x4 hi = *reinterpret_cast<const f32x4*>(xp + 4);
#pragma unroll
      for (int i = 0; i < 4; ++i) { a[i] = (__bf16)lo[i]; a[i + 4] = (__bf16)hi[i]; }
    }
    bf16x8 bx = *reinterpret_cast<const bf16x8*>(bxlds + (w * 8 + k8) * 1024 + lane * 16);
    if (k8 & 1) axb = __builtin_amdgcn_mfma_f32_16x16x32_bf16(a, bx, axb, 0, 0, 0);
    else        axa = __builtin_amdgcn_mfma_f32_16x16x32_bf16(a, bx, axa, 0, 0, 0);
  }

#pragma unroll 1
  for (int t = 0; t < TT; ++t) {
    f32x4 acc_a = axa;
    f32x4 acc_b = axb;

    if (t > 0) {
      // ---- one-round-trip exchange: 8 self-validating h dwords per lane
      const unsigned* hp = hseq + (size_t)(t & 1) * 65536
                         + (size_t)(b0 + l15) * HSZ + w * 32 + l4 * 8;
      const unsigned tg = (unsigned)t;
      uint4v A, B;
      for (;;) {
        asm volatile("global_load_dwordx4 %0, %2, off sc0 sc1\n\t"
                     "global_load_dwordx4 %1, %2, off offset:16 sc0 sc1\n\t"
                     "s_waitcnt vmcnt(0)"
                     : "=&v"(A), "=&v"(B) : "v"(hp) : "memory");
        bool ok = ((A[0] >> 16) == tg) & ((A[1] >> 16) == tg) &
                  ((A[2] >> 16) == tg) & ((A[3] >> 16) == tg) &
                  ((B[0] >> 16) == tg) & ((B[1] >> 16) == tg) &
                  ((B[2] >> 16) == tg) & ((B[3] >> 16) == tg);
        if (__all((int)ok)) break;
        __builtin_amdgcn_s_sleep(1);
      }
      __builtin_amdgcn_sched_barrier(0);
      // pack 8 lo16 -> A-frag chunk kt=w; dedupe via LDS
      unsigned p0 = (A[0] & 0xFFFFu) | (A[1] << 16);
      unsigned p1 = (A[2] & 0xFFFFu) | (A[3] << 16);
      unsigned p2 = (B[0] & 0xFFFFu) | (B[1] << 16);
      unsigned p3 = (B[2] & 0xFFFFu) | (B[3] << 16);
      uint4v pk = {p0, p1, p2, p3};
      *reinterpret_cast<uint4v*>(hxl[t & 1] + w * 1024 + lane * 16) = pk;
    }
    __syncthreads();   // hxl[t&1] complete (t=0: bxlds/plain sync)

    if (t > 0) {
      // ---- critical MFMAs: acc += h(t) @ Wh — split chains (depth 4)
#pragma unroll
      for (int kt = 0; kt < 8; ++kt) {
        bf16x8 a = *reinterpret_cast<const bf16x8*>(hxl[t & 1] + kt * 1024 + lane * 16);
        if (kt & 1) acc_b = __builtin_amdgcn_mfma_f32_16x16x32_bf16(a, Bh[kt], acc_b, 0, 0, 0);
        else        acc_a = __builtin_amdgcn_mfma_f32_16x16x32_bf16(a, Bh[kt], acc_a, 0, 0, 0);
      }
    }

    // ---- in-wave butterfly combine (4-lane gate groups)
    f32x4 av;
#pragma unroll
    for (int r = 0; r < 4; ++r) {
      float vr = acc_a[r] + acc_b[r];
      float p  = isg ? 2.f * vr : vr;
      float s  = 1.f / (1.f + __expf(-p));
      av[r] = isg ? (2.f * s - 1.f) : s;   // tanh(v) = 2*sigmoid(2v)-1
    }
    f32x4 bv, v0, v1, c0, c1;
#pragma unroll
    for (int r = 0; r < 4; ++r) bv[r] = __shfl_xor(av[r], 1);
#pragma unroll
    for (int r = 0; r < 4; ++r) {
      v0[r] = (gate & 1) ? bv[r] : av[r];   // even-gate value (i or g)
      v1[r] = (gate & 1) ? av[r] : bv[r];   // odd-gate value (f or o)
    }
#pragma unroll
    for (int r = 0; r < 4; ++r) { c0[r] = __shfl_xor(v0[r], 2); c1[r] = __shfl_xor(v1[r], 2); }
    f32x4 hv;
#pragma unroll
    for (int r = 0; r < 4; ++r) {
      float iv = (gate & 2) ? c0[r] : v0[r];
      float fv = (gate & 2) ? c1[r] : v1[r];
      float gv = (gate & 2) ? v0[r] : c0[r];
      float ov = (gate & 2) ? v1[r] : c1[r];
      float cn = fv * cst[r] + iv * gv;
      cst[r] = cn;
      float s2 = 1.f / (1.f + __expf(-2.f * cn));
      hv[r] = ov * (2.f * s2 - 1.f);
    }
    // lane publishes row r = gate (static selects)
    float hsel = (gate == 0) ? hv[0] : (gate == 1) ? hv[1] : (gate == 2) ? hv[2] : hv[3];
    float csel = (gate == 0) ? cst[0] : (gate == 1) ? cst[1] : (gate == 2) ? cst[2] : cst[3];

    if (t + 1 < TT) {
      // ---- publish h(t+1) immediately: {seq16, bf16}, fire-and-forget
      __bf16 hb16 = (__bf16)hsel;
      unsigned hvd = ((unsigned)(t + 1) << 16)
                   | (unsigned)__builtin_bit_cast(unsigned short, hb16);
      unsigned* hp2 = hseq + (size_t)((t + 1) & 1) * 65536
                    + (size_t)(b0 + l4 * 4 + gate) * HSZ + (j * 32 + w * 4 + hcg);
      asm volatile("global_store_dword %0, %1, off sc0 sc1" :: "v"(hp2), "v"(hvd) : "memory");

      // ---- shadowed: acc_x = bias + x_{t+1} @ Wx (loads inline; Bx from LDS)
      axa = splat4(bias_v);
      axb = f32x4{0.f, 0.f, 0.f, 0.f};
#pragma unroll
      for (int k8 = 0; k8 < 8; ++k8) {
        bf16x8 a;
        if constexpr (XBF) {
          a = *reinterpret_cast<const bf16x8*>(
              xbf + (size_t)(b0 + l15) * (TT * XSZ) + (size_t)(t + 1) * XSZ + k8 * 32 + l4 * 8);
        } else {
          const float* xp = xf32 + (size_t)(b0 + l15) * (TT * XSZ)
                          + (size_t)(t + 1) * XSZ + k8 * 32 + l4 * 8;
          f32x4 lo = *reinterpret_cast<const f32x4*>(xp);
          f32x4 hi = *reinterpret_cast<const f32x4*>(xp + 4);
#pragma unroll
          for (int i = 0; i < 4; ++i) { a[i] = (__bf16)lo[i]; a[i + 4] = (__bf16)hi[i]; }
        }
        bf16x8 bx = *reinterpret_cast<const bf16x8*>(bxlds + (w * 8 + k8) * 1024 + lane * 16);
        if (k8 & 1) axb = __builtin_amdgcn_mfma_f32_16x16x32_bf16(a, bx, axb, 0, 0, 0);
        else        axa = __builtin_amdgcn_mfma_f32_16x16x32_bf16(a, bx, axa, 0, 0, 0);
      }
    } else {
      // ---- final step: emit (h_T, c_T) f32
      float* op = out + (size_t)(b0 + l4 * 4 + gate) * HSZ + (j * 32 + w * 4 + hcg);
      op[0] = hsel;
      op[(size_t)BB * HSZ] = csel;
    }
  }
}

extern "C" void kernel_launch(void* const* d_in, const int* in_sizes, int n_in,
                              void* d_out, int out_size, void* d_ws, size_t ws_size,
                              hipStream_t stream) {
  const float* x = (const float*)d_in[0];
  const float *wx[4], *wh[4], *bx[4], *bh[4];
  for (int g = 0; g < 4; ++g) {          // dict order: wx, wh, bx, bh per gate (i,f,g,o)
    wx[g] = (const float*)d_in[1 + 4 * g];
    wh[g] = (const float*)d_in[2 + 4 * g];
    bx[g] = (const float*)d_in[3 + 4 * g];
    bh[g] = (const float*)d_in[4 + 4 * g];
  }

  char* ws = (char*)d_ws;
  float*    bias = (float*)ws;                                   // 4 KB
  bf16_t*   Wtf  = (bf16_t*)(ws + 4096);                         // 1 MB
  unsigned* hseq = (unsigned*)(ws + 4096 + 1048576);             // 512 KB (2 x 64K dwords)
  bf16_t*   xbf  = (bf16_t*)(ws + 4096 + 1048576 + 524288);      // 64 MB (optional)
  const size_t need_xbf = 4096 + 1048576 + 524288 + (size_t)BB * TT * XSZ * 2;

  prep_bias<<<dim3(4), dim3(256), 0, stream>>>(bx[0], bh[0], bx[1], bh[1],
                                               bx[2], bh[2], bx[3], bh[3], bias);
  prep_wtf<<<dim3(256), dim3(256), 0, stream>>>(wx[0], wh[0], wx[1], wh[1],
                                                wx[2], wh[2], wx[3], wh[3], Wtf);
  if (ws_size >= need_xbf) {
    prep_xbf<<<dim3((BB * TT * XSZ / 8) / 256), dim3(256), 0, stream>>>(x, xbf);
    lstm_seq<true><<<dim3(128), dim3(512), 0, stream>>>(xbf, Wtf, bias, hseq,
                                                        (float*)d_out);
  } else {
    lstm_seq<false><<<dim3(128), dim3(512), 0, stream>>>(x, Wtf, bias, hseq,
                                                         (float*)d_out);
  }
}